// Round 8
// baseline (1170.179 us; speedup 1.0000x reference)
//
#include <hip/hip_runtime.h>
#include <math.h>

constexpr int D    = 128;
constexpr int BT   = 128;    // targets per bucket (bucket = tgt >> 7)
constexpr int TILE = 4096;   // edges per bucketize block

using bf16x8 = __attribute__((ext_vector_type(8))) short;
using f32x4  = __attribute__((ext_vector_type(4))) float;
#define MFMA16 __builtin_amdgcn_mfma_f32_16x16x32_bf16

__device__ __forceinline__ unsigned short f2bf(float f) {
    unsigned u = __builtin_bit_cast(unsigned, f);
    u = (u + 0x7FFF + ((u >> 16) & 1)) >> 16;   // RNE
    return (unsigned short)u;
}

// Native LDS float add. HIP's atomicAdd(float*) on __shared__ lowers to a CAS
// retry loop (r7: 1108us, all pipes idle). ds_add_f32 is fire-and-forget; the
// s_waitcnt lgkmcnt(0) that __syncthreads emits drains it at hardware level.
// addrspacecast generic->local = trunc to 32-bit LDS offset on AMDGPU.
typedef __attribute__((address_space(3))) float lds_f32;
__device__ __forceinline__ void lds_fadd(float* p, float v) {
    lds_f32* lp = (lds_f32*)p;
    asm volatile("ds_add_f32 %0, %1" :: "v"(lp), "v"(v) : "memory");
}

// ---------------------------------------------------------------------------
// prep: fused by block range.
//   [0, GA+GB)        : bucketize edges (LDS histogram -> coalesced runs)
//   [GA+GB, +GCONV)   : x f32 row-major -> x_bfs bf16 SLICE-major [4][N][32]
//   [GA+GB+GCONV,+24) : repack weights -> MFMA B-fragment order
// ---------------------------------------------------------------------------
__global__ __launch_bounds__(256)
void prep_kernel(const float* __restrict__ x, unsigned short* __restrict__ x_bfs,
                 const int* __restrict__ ea, int Ea,
                 const int* __restrict__ eb, int Eb,
                 unsigned int* __restrict__ ent_a, int* __restrict__ cnt_a,
                 unsigned int* __restrict__ ent_b, int* __restrict__ cnt_b,
                 const float* __restrict__ Wl, const float* __restrict__ Wr,
                 const float* __restrict__ Wp,
                 unsigned short* __restrict__ WlB, unsigned short* __restrict__ WrB,
                 unsigned short* __restrict__ WpB,
                 int N, int NBKT, int CAP, int GA, int GB, int GCONV)
{
    __shared__ int hist[512];
    __shared__ int base[512];

    const int bid = blockIdx.x;
    const int t   = threadIdx.x;

    if (bid < GA + GB) {
        // ---- bucketize ----
        const int type = (bid >= GA);
        const int* e   = type ? eb : ea;
        const int  E   = type ? Eb : Ea;
        unsigned int* ent = type ? ent_b : ent_a;
        int* cnt          = type ? cnt_b : cnt_a;
        const int i0 = (bid - type * GA) * TILE;

        for (int h = t; h < NBKT; h += 256) hist[h] = 0;
        __syncthreads();

        int tgts[16];
        #pragma unroll
        for (int j = 0; j < 16; ++j) {
            int i = i0 + j * 256 + t;
            tgts[j] = (i < E) ? e[(size_t)E + i] : -1;
            if (tgts[j] >= 0) atomicAdd(&hist[tgts[j] >> 7], 1);
        }
        __syncthreads();

        for (int h = t; h < NBKT; h += 256) {
            base[h] = (hist[h] > 0) ? atomicAdd(&cnt[h], hist[h]) : 0;
            hist[h] = 0;
        }
        __syncthreads();

        #pragma unroll
        for (int j = 0; j < 16; ++j) {
            int i = i0 + j * 256 + t;
            if (tgts[j] >= 0) {
                int b   = tgts[j] >> 7;
                int pos = base[b] + atomicAdd(&hist[b], 1);
                if (pos < CAP)
                    ent[(size_t)b * CAP + pos] = ((unsigned)e[i] << 7) | (tgts[j] & 127);
            }
        }
    } else if (bid < GA + GB + GCONV) {
        // ---- convert: slice-major x_bfs[s][n][c], s = col>>5 ----
        const int total4 = N * 32;            // float4s
        for (int i = (bid - GA - GB) * 256 + t; i < total4; i += GCONV * 256) {
            int n  = i >> 5;
            int j4 = i & 31;
            float4 v = reinterpret_cast<const float4*>(x)[i];
            ushort4 o;
            o.x = f2bf(v.x); o.y = f2bf(v.y); o.z = f2bf(v.z); o.w = f2bf(v.w);
            int s = j4 >> 3, c = (j4 & 7) * 4;
            *reinterpret_cast<ushort4*>(x_bfs + ((size_t)s * N + n) * 32 + c) = o;
        }
    } else {
        // ---- repack weights ----
        int gw = ((bid - GA - GB - GCONV) * 256 + t) >> 6;   // 0..95
        int l  = t & 63;
        const float* W = (gw < 32) ? Wl : (gw < 64) ? Wr : Wp;
        unsigned short* O = (gw < 32) ? WlB : (gw < 64) ? WrB : WpB;
        int ktnt = gw & 31, kt = ktnt >> 3, nt = ktnt & 7;
        bf16x8 v;
        #pragma unroll
        for (int j = 0; j < 8; ++j)
            v[j] = (short)f2bf(W[(size_t)(kt * 32 + (l >> 4) * 8 + j) * D + nt * 16 + (l & 15)]);
        *reinterpret_cast<bf16x8*>(O + ((size_t)ktnt * 64 + l) * 8) = v;
    }
}

// ---------------------------------------------------------------------------
// agg: edge-parallel aggregation into LDS f32 accumulators, native ds_add_f32.
// grid = 4 slices x 2 types x NBKT; slice = bid&3 keeps each XCD on one
// 3.2 MB x-slice (L2-resident, FETCH 21 MB verified r5/r6).
// 8 lanes per edge: uint2 load (8 B of the 64 B slice row), 4x ds_add_f32.
// acc row stride 33 f32 -> bank=(tgt+4c+j)&31 row-rotated, ~2-way conflicts.
// All edge iterations independent -> no dependent chains, latency hidden.
// ---------------------------------------------------------------------------
__global__ __launch_bounds__(256)
void agg_lds_kernel(const unsigned short* __restrict__ x_bfs,
                    const unsigned int* __restrict__ ent_a, const int* __restrict__ cnt_a,
                    const unsigned int* __restrict__ ent_b, const int* __restrict__ cnt_b,
                    unsigned short* __restrict__ mean_a_s,
                    unsigned short* __restrict__ mean_b_s,
                    int N, int NBKT, int CAP)
{
    __shared__ float accs[BT * 33];   // 16.9 KB, +1-f32 row pad for bank rotation
    __shared__ int   hcnt[BT];

    const int bid   = blockIdx.x;
    const int slice = bid & 3;
    const int tb    = bid >> 2;                // (type,bucket)
    const int type  = (tb >= NBKT);
    const int k     = tb - type * NBKT;

    const int t   = threadIdx.x;
    const int sub = t >> 3;                    // edge slot 0..31
    const int c   = t & 7;                     // which 8B of the 64B row

    for (int i = t; i < BT * 33; i += 256) accs[i] = 0.f;
    if (t < BT) hcnt[t] = 0;
    __syncthreads();

    const unsigned int* ent = (type ? ent_b : ent_a) + (size_t)k * CAP;
    const int cnt = min((type ? cnt_b : cnt_a)[k], CAP);
    const uint2* xs = (const uint2*)(x_bfs + (size_t)slice * N * 32);

    #pragma unroll 2
    for (int i = sub; i < cnt; i += 32) {
        unsigned e   = ent[i];                 // 8 lanes share one dword
        unsigned src = e >> 7;
        unsigned tl  = e & 127u;
        uint2 v = xs[src * 8 + c];
        float* ap = accs + tl * 33 + (c << 2);
        lds_fadd(ap + 0, __builtin_bit_cast(float, v.x << 16));
        lds_fadd(ap + 1, __builtin_bit_cast(float, v.x & 0xffff0000u));
        lds_fadd(ap + 2, __builtin_bit_cast(float, v.y << 16));
        lds_fadd(ap + 3, __builtin_bit_cast(float, v.y & 0xffff0000u));
        if (c == 0) atomicAdd(&hcnt[tl], 1);
    }
    __syncthreads();

    // ---- epilogue: scale by 1/deg, pack bf16, coalesced store ----
    unsigned short* mean = (type ? mean_b_s : mean_a_s) + (size_t)slice * N * 32;
    for (int i = t; i < BT * 16; i += 256) {
        int n  = i >> 4;
        int cc = i & 15;
        int gn = k * BT + n;
        if (gn < N) {
            float r  = 1.0f / fmaxf((float)hcnt[n], 1.0f);
            float f0 = accs[n * 33 + cc * 2]     * r;
            float f1 = accs[n * 33 + cc * 2 + 1] * r;
            unsigned o = ((unsigned)f2bf(f1) << 16) | f2bf(f0);
            *(unsigned*)(mean + (size_t)gn * 32 + cc * 2) = o;
        }
    }
}

// ---------------------------------------------------------------------------
// MFMA GEMM (round-3 structure; A-fragment loads slice-major). Unchanged.
// ---------------------------------------------------------------------------
__global__ __launch_bounds__(256)
void gemm_kernel(const unsigned short* __restrict__ mean_a_s,
                 const unsigned short* __restrict__ mean_b_s,
                 const unsigned short* __restrict__ x_bfs,
                 const unsigned short* __restrict__ WlB,
                 const unsigned short* __restrict__ WrB,
                 const unsigned short* __restrict__ WpB,
                 const float* __restrict__ bl, const float* __restrict__ bp,
                 float* __restrict__ out, int N)
{
    __shared__ unsigned short hA[64 * D];
    __shared__ unsigned short hB[64 * D];

    const int t = threadIdx.x, w = t >> 6, l = t & 63;
    const int q = l & 15;
    const int kg = l >> 4;
    const int node0 = blockIdx.x * 64 + w * 16;
    const int arow = min(node0 + q, N - 1);

    bf16x8 fa[4], fb[4], fx[4];
    #pragma unroll
    for (int kt = 0; kt < 4; ++kt) {
        size_t o = ((size_t)kt * N + arow) * 32 + kg * 8;   // slice kt
        fa[kt] = *reinterpret_cast<const bf16x8*>(mean_a_s + o);
        fb[kt] = *reinterpret_cast<const bf16x8*>(mean_b_s + o);
        fx[kt] = *reinterpret_cast<const bf16x8*>(x_bfs + o);
    }

    #pragma unroll
    for (int nt = 0; nt < 8; ++nt) {
        f32x4 ca = {0.f, 0.f, 0.f, 0.f};
        f32x4 cb = {0.f, 0.f, 0.f, 0.f};
        #pragma unroll
        for (int kt = 0; kt < 4; ++kt) {
            const size_t fo = ((size_t)(kt * 8 + nt) * 64 + l) * 8;
            bf16x8 wl = *reinterpret_cast<const bf16x8*>(WlB + fo);
            bf16x8 wr = *reinterpret_cast<const bf16x8*>(WrB + fo);
            ca = MFMA16(fa[kt], wl, ca, 0, 0, 0);
            ca = MFMA16(fx[kt], wr, ca, 0, 0, 0);
            cb = MFMA16(fb[kt], wl, cb, 0, 0, 0);
            cb = MFMA16(fx[kt], wr, cb, 0, 0, 0);
        }
        float blv = bl[nt * 16 + q];
        #pragma unroll
        for (int r = 0; r < 4; ++r) {
            int lrow = w * 16 + kg * 4 + r;
            int byte = lrow * 256 + (nt * 16 + q) * 2;
            byte ^= ((lrow & 7) << 4);
            *reinterpret_cast<unsigned short*>(reinterpret_cast<char*>(hA) + byte) = f2bf(ca[r] + blv);
            *reinterpret_cast<unsigned short*>(reinterpret_cast<char*>(hB) + byte) = f2bf(cb[r] + blv);
        }
    }
    __syncthreads();

    bf16x8 ga[4], gb[4];
    #pragma unroll
    for (int kt = 0; kt < 4; ++kt) {
        int lrow = w * 16 + q;
        int byte = lrow * 256 + kt * 64 + kg * 16;
        byte ^= ((lrow & 7) << 4);
        ga[kt] = *reinterpret_cast<bf16x8*>(reinterpret_cast<char*>(hA) + byte);
        gb[kt] = *reinterpret_cast<bf16x8*>(reinterpret_cast<char*>(hB) + byte);
    }

    f32x4 la[8], lb[8];
    #pragma unroll
    for (int nt = 0; nt < 8; ++nt) {
        la[nt] = f32x4{0.f, 0.f, 0.f, 0.f};
        lb[nt] = f32x4{0.f, 0.f, 0.f, 0.f};
        #pragma unroll
        for (int kt = 0; kt < 4; ++kt) {
            const size_t fo = ((size_t)(kt * 8 + nt) * 64 + l) * 8;
            bf16x8 wp = *reinterpret_cast<const bf16x8*>(WpB + fo);
            la[nt] = MFMA16(ga[kt], wp, la[nt], 0, 0, 0);
            lb[nt] = MFMA16(gb[kt], wp, lb[nt], 0, 0, 0);
        }
        float bpv = bp[nt * 16 + q];
        #pragma unroll
        for (int r = 0; r < 4; ++r) { la[nt][r] += bpv; lb[nt][r] += bpv; }
    }

    #pragma unroll
    for (int r = 0; r < 4; ++r) {
        float ma = -INFINITY, mb = -INFINITY;
        #pragma unroll
        for (int nt = 0; nt < 8; ++nt) {
            ma = fmaxf(ma, la[nt][r]);
            mb = fmaxf(mb, lb[nt][r]);
        }
        #pragma unroll
        for (int o = 1; o < 16; o <<= 1) {
            ma = fmaxf(ma, __shfl_xor(ma, o, 64));
            mb = fmaxf(mb, __shfl_xor(mb, o, 64));
        }
        float ea[8], eb[8], sa = 0.f, sb = 0.f;
        #pragma unroll
        for (int nt = 0; nt < 8; ++nt) {
            ea[nt] = __expf(la[nt][r] - ma); sa += ea[nt];
            eb[nt] = __expf(lb[nt][r] - mb); sb += eb[nt];
        }
        #pragma unroll
        for (int o = 1; o < 16; o <<= 1) {
            sa += __shfl_xor(sa, o, 64);
            sb += __shfl_xor(sb, o, 64);
        }
        float ra = 0.5f / sa, rb = 0.5f / sb;
        int grow = node0 + kg * 4 + r;
        if (grow < N) {
            float* o = out + (size_t)grow * D + q;
            #pragma unroll
            for (int nt = 0; nt < 8; ++nt)
                o[nt * 16] = ea[nt] * ra + eb[nt] * rb;
        }
    }
}

// ---------------------------------------------------------------------------
extern "C" void kernel_launch(void* const* d_in, const int* in_sizes, int n_in,
                              void* d_out, int out_size, void* d_ws, size_t ws_size,
                              hipStream_t stream)
{
    const float* x  = (const float*)d_in[0];
    const float* Wl = (const float*)d_in[1];
    const float* bl = (const float*)d_in[2];
    const float* Wr = (const float*)d_in[3];
    const float* Wp = (const float*)d_in[4];
    const float* bp = (const float*)d_in[5];
    const int*   ea = (const int*)d_in[6];
    const int*   eb = (const int*)d_in[7];

    const int N  = in_sizes[0] / D;
    const int Ea = in_sizes[6] / 2;
    const int Eb = in_sizes[7] / 2;

    const int NBKT = (N + BT - 1) / BT;
    const int Emax = Ea > Eb ? Ea : Eb;
    int CAP = (int)(((long long)Emax * BT / N) * 5 / 4 + 128);
    CAP = (CAP + 7) & ~7;

    unsigned int* ent_a = (unsigned int*)d_ws;              // NBKT*CAP
    unsigned int* ent_b = ent_a + (size_t)NBKT * CAP;
    int* cnt_a = (int*)(ent_b + (size_t)NBKT * CAP);        // NBKT
    int* cnt_b = cnt_a + NBKT;
    uintptr_t p = (uintptr_t)(cnt_b + NBKT);
    p = (p + 15) & ~(uintptr_t)15;
    unsigned short* x_bfs    = (unsigned short*)p;          // [4][N][32]
    unsigned short* mean_a_s = x_bfs + (size_t)N * D;
    unsigned short* mean_b_s = mean_a_s + (size_t)N * D;
    unsigned short* WlB      = mean_b_s + (size_t)N * D;
    unsigned short* WrB      = WlB + D * D;
    unsigned short* WpB      = WrB + D * D;

    hipMemsetAsync(cnt_a, 0, sizeof(int) * 2 * (size_t)NBKT, stream);

    const int GA = (Ea + TILE - 1) / TILE;
    const int GB = (Eb + TILE - 1) / TILE;
    const int GCONV = 512;
    prep_kernel<<<GA + GB + GCONV + 24, 256, 0, stream>>>(
        x, x_bfs, ea, Ea, eb, Eb, ent_a, cnt_a, ent_b, cnt_b,
        Wl, Wr, Wp, WlB, WrB, WpB, N, NBKT, CAP, GA, GB, GCONV);

    agg_lds_kernel<<<8 * NBKT, 256, 0, stream>>>(
        x_bfs, ent_a, cnt_a, ent_b, cnt_b, mean_a_s, mean_b_s, N, NBKT, CAP);

    gemm_kernel<<<(N + 63) / 64, 256, 0, stream>>>(
        mean_a_s, mean_b_s, x_bfs, WlB, WrB, WpB, bl, bp, (float*)d_out, N);
}

// Round 9
// 176.249 us; speedup vs baseline: 6.6393x; 6.6393x over previous
//
#include <hip/hip_runtime.h>
#include <math.h>

constexpr int D    = 128;
constexpr int BT   = 128;    // targets per bucket (bucket = tgt >> 7)
constexpr int TILE = 4096;   // edges per bucketize block

using bf16x8 = __attribute__((ext_vector_type(8))) short;
using f32x4  = __attribute__((ext_vector_type(4))) float;
#define MFMA16 __builtin_amdgcn_mfma_f32_16x16x32_bf16

__device__ __forceinline__ unsigned short f2bf(float f) {
    unsigned u = __builtin_bit_cast(unsigned, f);
    u = (u + 0x7FFF + ((u >> 16) & 1)) >> 16;   // RNE
    return (unsigned short)u;
}

// ---------------------------------------------------------------------------
// wprod: Wlp = Wl@Wp, Wrp = Wr@Wp (f32 compute), written directly in MFMA
// B-fragment bf16 layout. Block 0 also computes cvec = bl@Wp + bp (f32).
// grid = 2 blocks (one per product). Frag: lane l elem j =
// P[kt*32 + 8*(l>>4) + j][nt*16 + (l&15)], stored O[((kt*8+nt)*64+l)*8+j].
// ---------------------------------------------------------------------------
__global__ __launch_bounds__(256)
void wprod_kernel(const float* __restrict__ Wl, const float* __restrict__ Wr,
                  const float* __restrict__ Wp,
                  const float* __restrict__ bl, const float* __restrict__ bp,
                  unsigned short* __restrict__ WlpB, unsigned short* __restrict__ WrpB,
                  float* __restrict__ cvec)
{
    __shared__ float wm[128 * 128];   // 64 KiB
    __shared__ float wp[128 * 128];   // 64 KiB

    const float* Wm = blockIdx.x ? Wr : Wl;
    unsigned short* OB = blockIdx.x ? WrpB : WlpB;
    const int t = threadIdx.x;

    for (int i = t; i < 4096; i += 256) {
        reinterpret_cast<float4*>(wm)[i] = reinterpret_cast<const float4*>(Wm)[i];
        reinterpret_cast<float4*>(wp)[i] = reinterpret_cast<const float4*>(Wp)[i];
    }
    __syncthreads();

    const int w = t >> 6, l = t & 63;
    const int r0 = w * 32 + (l >> 4) * 8;   // 8 rows r0..r0+7
    const int c0 = l & 15;                  // col = nt*16 + c0

    float acc[8][8];
    #pragma unroll
    for (int j = 0; j < 8; ++j)
        #pragma unroll
        for (int nt = 0; nt < 8; ++nt) acc[j][nt] = 0.f;

    for (int k = 0; k < 128; ++k) {
        float wpv[8];
        #pragma unroll
        for (int nt = 0; nt < 8; ++nt) wpv[nt] = wp[k * 128 + nt * 16 + c0];
        #pragma unroll
        for (int j = 0; j < 8; ++j) {
            float wmv = wm[(r0 + j) * 128 + k];
            #pragma unroll
            for (int nt = 0; nt < 8; ++nt) acc[j][nt] += wmv * wpv[nt];
        }
    }
    #pragma unroll
    for (int nt = 0; nt < 8; ++nt)
        #pragma unroll
        for (int j = 0; j < 8; ++j)
            OB[((size_t)(w * 8 + nt) * 64 + l) * 8 + j] = f2bf(acc[j][nt]);

    if (blockIdx.x == 0 && t < 128) {
        float s = bp[t];
        for (int k = 0; k < 128; ++k) s += bl[k] * wp[k * 128 + t];
        cvec[t] = s;
    }
}

// ---------------------------------------------------------------------------
// prep: [0,GA+GB) bucketize edges; [GA+GB,+GCONV) x f32 -> bf16 ROW-major.
// ---------------------------------------------------------------------------
__global__ __launch_bounds__(256)
void prep_kernel(const float* __restrict__ x, unsigned short* __restrict__ x_bf,
                 const int* __restrict__ ea, int Ea,
                 const int* __restrict__ eb, int Eb,
                 unsigned int* __restrict__ ent_a, int* __restrict__ cnt_a,
                 unsigned int* __restrict__ ent_b, int* __restrict__ cnt_b,
                 int N, int NBKT, int CAP, int GA, int GB, int GCONV)
{
    __shared__ int hist[512];
    __shared__ int base[512];

    const int bid = blockIdx.x;
    const int t   = threadIdx.x;

    if (bid < GA + GB) {
        const int type = (bid >= GA);
        const int* e   = type ? eb : ea;
        const int  E   = type ? Eb : Ea;
        unsigned int* ent = type ? ent_b : ent_a;
        int* cnt          = type ? cnt_b : cnt_a;
        const int i0 = (bid - type * GA) * TILE;

        for (int h = t; h < NBKT; h += 256) hist[h] = 0;
        __syncthreads();

        int tgts[16];
        #pragma unroll
        for (int j = 0; j < 16; ++j) {
            int i = i0 + j * 256 + t;
            tgts[j] = (i < E) ? e[(size_t)E + i] : -1;
            if (tgts[j] >= 0) atomicAdd(&hist[tgts[j] >> 7], 1);
        }
        __syncthreads();

        for (int h = t; h < NBKT; h += 256) {
            base[h] = (hist[h] > 0) ? atomicAdd(&cnt[h], hist[h]) : 0;
            hist[h] = 0;
        }
        __syncthreads();

        #pragma unroll
        for (int j = 0; j < 16; ++j) {
            int i = i0 + j * 256 + t;
            if (tgts[j] >= 0) {
                int b   = tgts[j] >> 7;
                int pos = base[b] + atomicAdd(&hist[b], 1);
                if (pos < CAP)
                    ent[(size_t)b * CAP + pos] = ((unsigned)e[i] << 7) | (tgts[j] & 127);
            }
        }
    } else {
        const int total4 = N * 32;            // float4s
        for (int i = (bid - GA - GB) * 256 + t; i < total4; i += GCONV * 256) {
            float4 v = reinterpret_cast<const float4*>(x)[i];
            ushort4 o;
            o.x = f2bf(v.x); o.y = f2bf(v.y); o.z = f2bf(v.z); o.w = f2bf(v.w);
            reinterpret_cast<ushort4*>(x_bf)[i] = o;
        }
    }
}

// ---------------------------------------------------------------------------
// sort: per (type,bucket): LDS histogram + scan + scatter; persist sorted
// src list (ushort) + per-node offsets. (unchanged from r6, verified)
// ---------------------------------------------------------------------------
__global__ __launch_bounds__(512)
void sort_kernel(const unsigned int* __restrict__ ent_a, const int* __restrict__ cnt_a,
                 const unsigned int* __restrict__ ent_b, const int* __restrict__ cnt_b,
                 unsigned short* __restrict__ srcl_g, int* __restrict__ off_g,
                 int NBKT, int CAP)
{
    extern __shared__ __align__(16) char smem_raw[];
    int* tmp  = (int*)smem_raw;                          // CAP
    int* off  = tmp + CAP;                               // BT+1
    int* cur  = off + BT + 1;                            // BT
    int* wtot = cur + BT;                                // 2
    unsigned short* srcl = (unsigned short*)(wtot + 2);  // CAP

    const int bid  = blockIdx.x;
    const int type = (bid >= NBKT);
    const int k    = bid - type * NBKT;
    const unsigned int* ent = type ? ent_b : ent_a;
    const int cnt = min((type ? cnt_b : cnt_a)[k], CAP);

    const int t = threadIdx.x, l = t & 63, w = t >> 6;

    if (t < BT) off[t] = 0;
    __syncthreads();

    for (int i = t; i < cnt; i += 512) {
        unsigned e = ent[(size_t)k * CAP + i];
        tmp[i] = (int)e;
        atomicAdd(&off[e & (BT - 1)], 1);
    }
    __syncthreads();

    int v = 0, s = 0;
    if (t < BT) {
        v = off[t]; s = v;
        #pragma unroll
        for (int o = 1; o < 64; o <<= 1) {
            int u = __shfl_up(s, o, 64);
            if (l >= o) s += u;
        }
        if (l == 63) wtot[w] = s;
    }
    __syncthreads();
    if (t < BT) {
        int ex = ((w == 1) ? wtot[0] : 0) + s - v;
        off[t] = ex; cur[t] = ex;
    }
    if (t == 0) off[BT] = wtot[0] + wtot[1];
    __syncthreads();

    for (int i = t; i < cnt; i += 512) {
        unsigned e = (unsigned)tmp[i];
        int pos = atomicAdd(&cur[e & (BT - 1)], 1);
        srcl[pos] = (unsigned short)(e >> 7);
    }
    __syncthreads();

    for (int i = t; i < cnt; i += 512)
        srcl_g[(size_t)bid * CAP + i] = srcl[i];
    if (t <= BT)
        off_g[(size_t)bid * (BT + 1) + t] = off[t];
}

// ---------------------------------------------------------------------------
// gemmZ: Z_l = x@Wlp (SLICE-major bf16 [4][N][32], gathered next),
//        Z_r = x@Wrp + cvec (row-major bf16). One A input, 64 MFMA/wave,
//        no LDS roundtrip (GEMM2 algebraically eliminated).
// ---------------------------------------------------------------------------
__global__ __launch_bounds__(256)
void gemmz_kernel(const unsigned short* __restrict__ x_bf,
                  const unsigned short* __restrict__ WlpB,
                  const unsigned short* __restrict__ WrpB,
                  const float* __restrict__ cvec,
                  unsigned short* __restrict__ zl, unsigned short* __restrict__ zr,
                  int N)
{
    const int t = threadIdx.x, w = t >> 6, l = t & 63;
    const int q = l & 15, kg = l >> 4;
    const int node0 = blockIdx.x * 64 + w * 16;
    const int arow = min(node0 + q, N - 1);

    bf16x8 fx[4];
    #pragma unroll
    for (int kt = 0; kt < 4; ++kt)
        fx[kt] = *reinterpret_cast<const bf16x8*>(x_bf + (size_t)arow * D + kt * 32 + kg * 8);

    #pragma unroll
    for (int nt = 0; nt < 8; ++nt) {
        f32x4 cl = {0.f, 0.f, 0.f, 0.f};
        f32x4 cr = {0.f, 0.f, 0.f, 0.f};
        #pragma unroll
        for (int kt = 0; kt < 4; ++kt) {
            const size_t fo = ((size_t)(kt * 8 + nt) * 64 + l) * 8;
            bf16x8 wl = *reinterpret_cast<const bf16x8*>(WlpB + fo);
            bf16x8 wr = *reinterpret_cast<const bf16x8*>(WrpB + fo);
            cl = MFMA16(fx[kt], wl, cl, 0, 0, 0);
            cr = MFMA16(fx[kt], wr, cr, 0, 0, 0);
        }
        float cv = cvec[nt * 16 + q];
        const int sidx = nt >> 1;
        const int cin  = (nt & 1) * 16 + q;
        #pragma unroll
        for (int r = 0; r < 4; ++r) {
            int grow = node0 + kg * 4 + r;
            if (grow < N) {
                zl[((size_t)sidx * N + grow) * 32 + cin] = f2bf(cl[r]);
                zr[(size_t)grow * D + nt * 16 + q]       = f2bf(cr[r] + cv);
            }
        }
    }
}

// ---------------------------------------------------------------------------
// gather: grid = 4 slices x 2 types x NBKT (slice = bid&3 -> one 3.2MB
// Z_l slice per XCD, L2-resident — FETCH 21MB verified r5/r6).
// ILP fix vs r6: wave processes 4 NODES concurrently (quad q = node,
// 16 lanes x 4B = one 64B slice row per edge), loop to wave-uniform
// max(deg) with predicated accumulate. No cross-lane reduction: each lane
// owns its 2 output columns. 4 independent load chains per wave.
// ---------------------------------------------------------------------------
__global__ __launch_bounds__(256)
void gather_kernel(const unsigned* __restrict__ zl,       // [4][N][16] dwords
                   const unsigned short* __restrict__ srcl_g,
                   const int* __restrict__ off_g,
                   unsigned short* __restrict__ agg_a,
                   unsigned short* __restrict__ agg_b,
                   int N, int NBKT, int CAP)
{
    extern __shared__ __align__(16) char smem_raw[];
    int* off = (int*)smem_raw;                               // BT+1
    unsigned short* srcl = (unsigned short*)(off + BT + 1);  // CAP

    const int bid   = blockIdx.x;
    const int slice = bid & 3;
    const int tb    = bid >> 2;
    const int type  = (tb >= NBKT);
    const int k     = tb - type * NBKT;

    const int t = threadIdx.x, l = t & 63, w = t >> 6;
    const int q = l >> 4;                      // node within wave group
    const unsigned c = l & 15;                 // dword within 64B slice row

    const int cnt = off_g[(size_t)tb * (BT + 1) + BT];
    for (int i = t; i <= BT; i += 256)
        off[i] = off_g[(size_t)tb * (BT + 1) + i];
    for (int i = t; i < cnt; i += 256)
        srcl[i] = srcl_g[(size_t)tb * CAP + i];
    __syncthreads();

    const unsigned* zs = zl + (size_t)slice * N * 16;
    unsigned short* agg = (type ? agg_b : agg_a) + (size_t)slice * N * 32;

    #pragma unroll
    for (int pass = 0; pass < BT / 16; ++pass) {   // 8 passes x 16 nodes
        const int tt = pass * 16 + w * 4 + q;
        const int o0 = off[tt], o1 = off[tt + 1];
        const int deg = o1 - o0;
        int md = max(deg, __shfl_xor(deg, 16, 64));
        md = max(md, __shfl_xor(md, 32, 64));

        float a0 = 0.f, a1 = 0.f;
        #pragma unroll 4
        for (int j = 0; j < md; ++j) {
            const bool act = (j < deg);
            const int idx = o0 + (act ? j : 0);       // always in-bounds
            const unsigned s = srcl[idx];
            const unsigned v = zs[s * 16 + c];
            if (act) {
                a0 += __builtin_bit_cast(float, v << 16);
                a1 += __builtin_bit_cast(float, v & 0xffff0000u);
            }
        }
        const float r = 1.0f / fmaxf((float)deg, 1.0f);
        const int n = k * BT + tt;
        if (n < N) {
            unsigned o = ((unsigned)f2bf(a1 * r) << 16) | f2bf(a0 * r);
            *(unsigned*)(agg + (size_t)n * 32 + c * 2) = o;
        }
    }
}

// ---------------------------------------------------------------------------
// epilogue: logits_t = agg_t + Z_r (cvec already folded in), softmax over
// 128 cols (16 lanes x 8), average the two edge types, store f32.
// ---------------------------------------------------------------------------
__global__ __launch_bounds__(256)
void epi_kernel(const unsigned short* __restrict__ agg_a,
                const unsigned short* __restrict__ agg_b,
                const unsigned short* __restrict__ zr,
                float* __restrict__ out, int N)
{
    const int t = threadIdx.x;
    const int n = blockIdx.x * 16 + (t >> 4);
    const int c = t & 15;
    if (n >= N) return;

    const int s = c >> 2;
    const size_t aoff = ((size_t)s * N + n) * 32 + (c & 3) * 8;   // ushort idx
    uint4 va = *reinterpret_cast<const uint4*>(agg_a + aoff);
    uint4 vb = *reinterpret_cast<const uint4*>(agg_b + aoff);
    uint4 vz = *reinterpret_cast<const uint4*>(zr + (size_t)n * D + c * 8);

    unsigned ua[4] = {va.x, va.y, va.z, va.w};
    unsigned ub[4] = {vb.x, vb.y, vb.z, vb.w};
    unsigned uz[4] = {vz.x, vz.y, vz.z, vz.w};

    float la[8], lb[8];
    #pragma unroll
    for (int d = 0; d < 4; ++d) {
        float z0 = __builtin_bit_cast(float, uz[d] << 16);
        float z1 = __builtin_bit_cast(float, uz[d] & 0xffff0000u);
        la[2*d]   = __builtin_bit_cast(float, ua[d] << 16) + z0;
        la[2*d+1] = __builtin_bit_cast(float, ua[d] & 0xffff0000u) + z1;
        lb[2*d]   = __builtin_bit_cast(float, ub[d] << 16) + z0;
        lb[2*d+1] = __builtin_bit_cast(float, ub[d] & 0xffff0000u) + z1;
    }

    float ma = -INFINITY, mb = -INFINITY;
    #pragma unroll
    for (int j = 0; j < 8; ++j) { ma = fmaxf(ma, la[j]); mb = fmaxf(mb, lb[j]); }
    #pragma unroll
    for (int o = 1; o < 16; o <<= 1) {
        ma = fmaxf(ma, __shfl_xor(ma, o, 64));
        mb = fmaxf(mb, __shfl_xor(mb, o, 64));
    }
    float sa = 0.f, sb = 0.f;
    #pragma unroll
    for (int j = 0; j < 8; ++j) {
        la[j] = __expf(la[j] - ma); sa += la[j];
        lb[j] = __expf(lb[j] - mb); sb += lb[j];
    }
    #pragma unroll
    for (int o = 1; o < 16; o <<= 1) {
        sa += __shfl_xor(sa, o, 64);
        sb += __shfl_xor(sb, o, 64);
    }
    const float ra = 0.5f / sa, rb = 0.5f / sb;

    float4 o0, o1;
    o0.x = la[0]*ra + lb[0]*rb; o0.y = la[1]*ra + lb[1]*rb;
    o0.z = la[2]*ra + lb[2]*rb; o0.w = la[3]*ra + lb[3]*rb;
    o1.x = la[4]*ra + lb[4]*rb; o1.y = la[5]*ra + lb[5]*rb;
    o1.z = la[6]*ra + lb[6]*rb; o1.w = la[7]*ra + lb[7]*rb;
    float* op = out + (size_t)n * D + c * 8;
    *reinterpret_cast<float4*>(op)     = o0;
    *reinterpret_cast<float4*>(op + 4) = o1;
}

// ---------------------------------------------------------------------------
extern "C" void kernel_launch(void* const* d_in, const int* in_sizes, int n_in,
                              void* d_out, int out_size, void* d_ws, size_t ws_size,
                              hipStream_t stream)
{
    const float* x  = (const float*)d_in[0];
    const float* Wl = (const float*)d_in[1];
    const float* bl = (const float*)d_in[2];
    const float* Wr = (const float*)d_in[3];
    const float* Wp = (const float*)d_in[4];
    const float* bp = (const float*)d_in[5];
    const int*   ea = (const int*)d_in[6];
    const int*   eb = (const int*)d_in[7];

    const int N  = in_sizes[0] / D;
    const int Ea = in_sizes[6] / 2;
    const int Eb = in_sizes[7] / 2;

    const int NBKT = (N + BT - 1) / BT;
    const int Emax = Ea > Eb ? Ea : Eb;
    int CAP = (int)(((long long)Emax * BT / N) * 5 / 4 + 128);
    CAP = (CAP + 7) & ~7;

    unsigned int* ent_a = (unsigned int*)d_ws;              // NBKT*CAP
    unsigned int* ent_b = ent_a + (size_t)NBKT * CAP;
    int* cnt_a = (int*)(ent_b + (size_t)NBKT * CAP);        // NBKT
    int* cnt_b = cnt_a + NBKT;
    int* off_g = cnt_b + NBKT;                              // 2*NBKT*(BT+1)
    float* cvec = (float*)(off_g + (size_t)2 * NBKT * (BT + 1));  // 128
    uintptr_t p = (uintptr_t)(cvec + 128);
    p = (p + 15) & ~(uintptr_t)15;
    unsigned short* srcl_g = (unsigned short*)p;            // 2*NBKT*CAP
    unsigned short* x_bf   = srcl_g + (size_t)2 * NBKT * CAP;
    unsigned short* zl     = x_bf + (size_t)N * D;          // slice-major
    unsigned short* zr     = zl + (size_t)N * D;            // row-major
    unsigned short* agg_a  = zr + (size_t)N * D;            // slice-major
    unsigned short* agg_b  = agg_a + (size_t)N * D;
    unsigned short* WlpB   = agg_b + (size_t)N * D;         // frag layout
    unsigned short* WrpB   = WlpB + D * D;

    hipMemsetAsync(cnt_a, 0, sizeof(int) * 2 * (size_t)NBKT, stream);

    wprod_kernel<<<2, 256, 0, stream>>>(Wl, Wr, Wp, bl, bp, WlpB, WrpB, cvec);

    const int GA = (Ea + TILE - 1) / TILE;
    const int GB = (Eb + TILE - 1) / TILE;
    const int GCONV = 512;
    prep_kernel<<<GA + GB + GCONV, 256, 0, stream>>>(
        x, x_bf, ea, Ea, eb, Eb, ent_a, cnt_a, ent_b, cnt_b,
        N, NBKT, CAP, GA, GB, GCONV);

    const int smem_sort = CAP * 6 + (BT + 1 + BT + 2) * 4 + 16;
    sort_kernel<<<2 * NBKT, 512, smem_sort, stream>>>(
        ent_a, cnt_a, ent_b, cnt_b, srcl_g, off_g, NBKT, CAP);

    gemmz_kernel<<<(N + 63) / 64, 256, 0, stream>>>(
        x_bf, WlpB, WrpB, cvec, zl, zr, N);

    const int smem_gather = (BT + 1) * 4 + CAP * 2 + 16;
    gather_kernel<<<8 * NBKT, 256, smem_gather, stream>>>(
        (const unsigned*)zl, srcl_g, off_g, agg_a, agg_b, N, NBKT, CAP);

    epi_kernel<<<(N + 15) / 16, 256, 0, stream>>>(agg_a, agg_b, zr,
                                                  (float*)d_out, N);
}